// Round 2
// baseline (3100.363 us; speedup 1.0000x reference)
//
#include <hip/hip_runtime.h>
#include <hip/hip_bf16.h>
#include <math.h>

#define D_MODEL 512
#define N_LAYERS 4
#define D_STATE 16
#define D_CONV 4
#define D_INNER 1024
#define DT_RANK 32
#define BATCH 4
#define SEQ 2048
#define NTOK (BATCH*SEQ)   // 8192
#define NCHUNK 32
#define CL (SEQ/NCHUNK)    // 64
#define LOG2E 1.44269504f

// ---------------- LayerNorm: one wave per row of 512 ----------------
__global__ __launch_bounds__(256) void ln_kernel(const float* __restrict__ x,
                          const float* __restrict__ w, const float* __restrict__ b,
                          float* __restrict__ out)
{
    int wave = threadIdx.x >> 6;
    int lane = threadIdx.x & 63;
    int row = blockIdx.x * 4 + wave;
    const float* xr = x + (size_t)row * D_MODEL;
    float v[8];
    float s = 0.f;
#pragma unroll
    for (int i = 0; i < 8; ++i) { v[i] = xr[lane + i*64]; s += v[i]; }
#pragma unroll
    for (int off = 32; off > 0; off >>= 1) s += __shfl_xor(s, off, 64);
    float mu = s * (1.f/512.f);
    float q = 0.f;
#pragma unroll
    for (int i = 0; i < 8; ++i) { float d = v[i]-mu; q += d*d; }
#pragma unroll
    for (int off = 32; off > 0; off >>= 1) q += __shfl_xor(q, off, 64);
    float rstd = rsqrtf(q * (1.f/512.f) + 1e-5f);
    float* orow = out + (size_t)row * D_MODEL;
#pragma unroll
    for (int i = 0; i < 8; ++i) {
        int e = lane + i*64;
        orow[e] = (v[i]-mu)*rstd*w[e] + b[e];
    }
}

// ------- fp32 NT GEMM 64x64 (for N=64 x_proj): C=A@B^T (+resid) -------
__global__ __launch_bounds__(256) void gemm_nt(const float* __restrict__ A, int lda,
                        const float* __restrict__ B, int ldb,
                        float* __restrict__ C, int ldc,
                        const float* __restrict__ resid,
                        int K)
{
    __shared__ float As[16][68];
    __shared__ float Bs[16][68];
    int tid = threadIdx.x;
    int tx = tid & 15, ty = tid >> 4;
    int row0 = blockIdx.y * 64, col0 = blockIdx.x * 64;
    int lr = tid >> 2;          // 0..63
    int lk = (tid & 3) << 2;    // 0,4,8,12
    float acc[4][4] = {};
    const float* Ap = A + (size_t)(row0+lr)*lda + lk;
    const float* Bp = B + (size_t)(col0+lr)*ldb + lk;
    for (int k0 = 0; k0 < K; k0 += 16) {
        float4 a4 = *(const float4*)(Ap + k0);
        float4 b4 = *(const float4*)(Bp + k0);
        __syncthreads();
        As[lk+0][lr]=a4.x; As[lk+1][lr]=a4.y; As[lk+2][lr]=a4.z; As[lk+3][lr]=a4.w;
        Bs[lk+0][lr]=b4.x; Bs[lk+1][lr]=b4.y; Bs[lk+2][lr]=b4.z; Bs[lk+3][lr]=b4.w;
        __syncthreads();
#pragma unroll
        for (int k = 0; k < 16; ++k) {
            float ar[4], br[4];
#pragma unroll
            for (int i=0;i<4;++i) ar[i] = As[k][ty*4+i];
#pragma unroll
            for (int j=0;j<4;++j) br[j] = Bs[k][tx*4+j];
#pragma unroll
            for (int i=0;i<4;++i)
#pragma unroll
                for (int j=0;j<4;++j) acc[i][j] = fmaf(ar[i], br[j], acc[i][j]);
        }
    }
#pragma unroll
    for (int i=0;i<4;++i) {
        int r = row0 + ty*4 + i;
        float* crow = C + (size_t)r*ldc + col0 + tx*4;
#pragma unroll
        for (int j=0;j<4;++j) {
            float vv = acc[i][j];
            if (resid) vv += resid[(size_t)r*ldc + col0 + tx*4 + j];
            crow[j] = vv;
        }
    }
}

// ------- fp32 NT GEMM 128x128, 8x8 microtile (FMA-bound ratio) -------
__global__ __launch_bounds__(256) void gemm_nt128(const float* __restrict__ A, int lda,
                        const float* __restrict__ B, int ldb,
                        float* __restrict__ C, int ldc,
                        const float* __restrict__ resid,
                        int K)
{
    __shared__ float As[16][132];
    __shared__ float Bs[16][132];
    int tid = threadIdx.x;
    int row0 = blockIdx.y * 128, col0 = blockIdx.x * 128;
    int sr = tid >> 2;          // 0..63
    int sc = (tid & 3) << 2;    // 0,4,8,12
    int ty = tid >> 4;          // 0..15 -> rows ty*8..+7
    int tx = tid & 15;          // 0..15 -> cols tx*8..+7
    float acc[8][8] = {};
    const float* Ap = A + (size_t)(row0+sr)*lda + sc;
    const float* Bp = B + (size_t)(col0+sr)*ldb + sc;
    for (int k0 = 0; k0 < K; k0 += 16) {
        float4 a0 = *(const float4*)(Ap + k0);
        float4 a1 = *(const float4*)(Ap + (size_t)64*lda + k0);
        float4 b0 = *(const float4*)(Bp + k0);
        float4 b1 = *(const float4*)(Bp + (size_t)64*ldb + k0);
        __syncthreads();
        As[sc+0][sr]=a0.x; As[sc+1][sr]=a0.y; As[sc+2][sr]=a0.z; As[sc+3][sr]=a0.w;
        As[sc+0][sr+64]=a1.x; As[sc+1][sr+64]=a1.y; As[sc+2][sr+64]=a1.z; As[sc+3][sr+64]=a1.w;
        Bs[sc+0][sr]=b0.x; Bs[sc+1][sr]=b0.y; Bs[sc+2][sr]=b0.z; Bs[sc+3][sr]=b0.w;
        Bs[sc+0][sr+64]=b1.x; Bs[sc+1][sr+64]=b1.y; Bs[sc+2][sr+64]=b1.z; Bs[sc+3][sr+64]=b1.w;
        __syncthreads();
#pragma unroll
        for (int k = 0; k < 16; ++k) {
            float4 al = *(const float4*)&As[k][ty*8];
            float4 ah = *(const float4*)&As[k][ty*8+4];
            float4 bl = *(const float4*)&Bs[k][tx*8];
            float4 bh = *(const float4*)&Bs[k][tx*8+4];
            float ar[8] = {al.x,al.y,al.z,al.w,ah.x,ah.y,ah.z,ah.w};
            float br[8] = {bl.x,bl.y,bl.z,bl.w,bh.x,bh.y,bh.z,bh.w};
#pragma unroll
            for (int i=0;i<8;++i)
#pragma unroll
                for (int j=0;j<8;++j) acc[i][j] = fmaf(ar[i], br[j], acc[i][j]);
        }
    }
#pragma unroll
    for (int i=0;i<8;++i) {
        int r = row0 + ty*8 + i;
        float* crow = C + (size_t)r*ldc + col0 + tx*8;
        const float* rrow = resid ? resid + (size_t)r*ldc + col0 + tx*8 : nullptr;
#pragma unroll
        for (int j=0;j<8;++j) {
            float vv = acc[i][j];
            if (rrow) vv += rrow[j];
            crow[j] = vv;
        }
    }
}

// ---------------- causal depthwise conv (k=4) + SiLU ----------------
__global__ __launch_bounds__(256) void conv_silu(const float* __restrict__ xz,
                        const float* __restrict__ cw, const float* __restrict__ cb,
                        float* __restrict__ u)
{
    int idx = blockIdx.x * 256 + threadIdx.x;   // (b*SEQ+t)*1024 + d
    int d = idx & (D_INNER-1);
    int t = (idx >> 10) & (SEQ-1);
    float w0 = cw[d*4+0], w1 = cw[d*4+1], w2 = cw[d*4+2], w3 = cw[d*4+3];
    float s = cb[d];
    const float* base = xz + ((size_t)(idx >> 10))*2048 + d;  // [b][t][d] in xz
    if (t >= 3) s = fmaf(w0, base[-3*2048], s);
    if (t >= 2) s = fmaf(w1, base[-2*2048], s);
    if (t >= 1) s = fmaf(w2, base[-1*2048], s);
    s = fmaf(w3, base[0], s);
    u[idx] = s / (1.f + __expf(-s));
}

// ---------------- dt_proj (K=32) + bias + softplus ----------------
__global__ __launch_bounds__(256) void dt_softplus(const float* __restrict__ xdbl,
                        const float* __restrict__ dtw, const float* __restrict__ dtb,
                        float* __restrict__ delta)
{
    __shared__ float xr[DT_RANK];
    int i = blockIdx.x;
    if (threadIdx.x < DT_RANK) xr[threadIdx.x] = xdbl[(size_t)i*64 + threadIdx.x];
    __syncthreads();
#pragma unroll
    for (int jj = 0; jj < 4; ++jj) {
        int j = threadIdx.x + jj*256;
        const float* w = dtw + (size_t)j*DT_RANK;
        float s = dtb[j];
#pragma unroll
        for (int r = 0; r < DT_RANK; r += 4) {
            float4 w4 = *(const float4*)(w + r);
            s = fmaf(xr[r+0], w4.x, s);
            s = fmaf(xr[r+1], w4.y, s);
            s = fmaf(xr[r+2], w4.z, s);
            s = fmaf(xr[r+3], w4.w, s);
        }
        float sp = (s > 20.f) ? s : log1pf(expf(s));
        delta[(size_t)i*D_INNER + j] = sp;
    }
}

// ======== chunked parallel selective scan: 3 passes ========
// Pass A: per (b,d,chunk): P[n]=prod dA, S[n]=chunk-local scan from h=0
__global__ __launch_bounds__(256) void scan_partial(const float* __restrict__ delta,
                        const float* __restrict__ u,
                        const float* __restrict__ xdbl,
                        const float* __restrict__ A_log,
                        float* __restrict__ P, float* __restrict__ S)
{
    int d = blockIdx.x * 256 + threadIdx.x;   // 0..1023
    int c = blockIdx.y;                        // chunk
    int b = blockIdx.z;
    int t0 = c * CL;
    __shared__ float Bsh[CL][16];
    for (int i = threadIdx.x; i < CL*16; i += 256) {
        int tt = i >> 4, n = i & 15;
        Bsh[tt][n] = xdbl[((size_t)(b*SEQ + t0 + tt))*64 + 32 + n];
    }
    __syncthreads();
    float A2[D_STATE];
#pragma unroll
    for (int n = 0; n < D_STATE; ++n)
        A2[n] = -expf(A_log[(size_t)d*D_STATE + n]) * LOG2E;
    float p[D_STATE], h[D_STATE];
#pragma unroll
    for (int n = 0; n < D_STATE; ++n) { p[n] = 1.f; h[n] = 0.f; }
    const float* dl = delta + ((size_t)(b*SEQ + t0))*D_INNER + d;
    const float* ul = u     + ((size_t)(b*SEQ + t0))*D_INNER + d;
    for (int t = 0; t < CL; ++t) {
        float dv = dl[(size_t)t*D_INNER];
        float uv = ul[(size_t)t*D_INNER];
        float du = dv * uv;
#pragma unroll
        for (int n = 0; n < D_STATE; ++n) {
            float dA = exp2f(dv * A2[n]);
            p[n] *= dA;
            h[n] = fmaf(dA, h[n], Bsh[t][n] * du);
        }
    }
    size_t base = (((size_t)b*D_INNER + d)*NCHUNK + c)*16;
#pragma unroll
    for (int n = 0; n < D_STATE; n += 4) {
        *(float4*)&P[base+n] = make_float4(p[n],p[n+1],p[n+2],p[n+3]);
        *(float4*)&S[base+n] = make_float4(h[n],h[n+1],h[n+2],h[n+3]);
    }
}

// Pass B: sequential over chunks per (b,d): Hs[c] = h_start(chunk c)
__global__ __launch_bounds__(256) void scan_boundary(const float* __restrict__ P,
                        const float* __restrict__ S, float* __restrict__ Hs)
{
    int b = blockIdx.x >> 2;
    int d = ((blockIdx.x & 3) << 8) + threadIdx.x;
    size_t base = ((size_t)b*D_INNER + d)*NCHUNK*16;
    float h[D_STATE];
#pragma unroll
    for (int n = 0; n < D_STATE; ++n) h[n] = 0.f;
    for (int c = 0; c < NCHUNK; ++c) {
        size_t o = base + (size_t)c*16;
#pragma unroll
        for (int n = 0; n < D_STATE; n += 4) {
            *(float4*)&Hs[o+n] = make_float4(h[n],h[n+1],h[n+2],h[n+3]);
            float4 p4 = *(const float4*)&P[o+n];
            float4 s4 = *(const float4*)&S[o+n];
            h[n+0] = fmaf(p4.x, h[n+0], s4.x);
            h[n+1] = fmaf(p4.y, h[n+1], s4.y);
            h[n+2] = fmaf(p4.z, h[n+2], s4.z);
            h[n+3] = fmaf(p4.w, h[n+3], s4.w);
        }
    }
}

// Pass C: re-scan chunk from Hs, produce y -> (y+u*D)*silu(z) into yout
__global__ __launch_bounds__(256) void scan_final(const float* __restrict__ delta,
                        const float* __restrict__ u,
                        const float* __restrict__ xz,
                        float* __restrict__ yout,
                        const float* __restrict__ xdbl,
                        const float* __restrict__ A_log,
                        const float* __restrict__ Dp,
                        const float* __restrict__ Hs)
{
    int d = blockIdx.x * 256 + threadIdx.x;
    int c = blockIdx.y;
    int b = blockIdx.z;
    int t0 = c * CL;
    __shared__ float Bsh[CL][16];
    __shared__ float Csh[CL][16];
    for (int i = threadIdx.x; i < CL*16; i += 256) {
        int tt = i >> 4, n = i & 15;
        size_t xo = ((size_t)(b*SEQ + t0 + tt))*64;
        Bsh[tt][n] = xdbl[xo + 32 + n];
        Csh[tt][n] = xdbl[xo + 48 + n];
    }
    __syncthreads();
    float A2[D_STATE];
#pragma unroll
    for (int n = 0; n < D_STATE; ++n)
        A2[n] = -expf(A_log[(size_t)d*D_STATE + n]) * LOG2E;
    float Dd = Dp[d];
    float h[D_STATE];
    size_t hbase = (((size_t)b*D_INNER + d)*NCHUNK + c)*16;
#pragma unroll
    for (int n = 0; n < D_STATE; n += 4) {
        float4 h4 = *(const float4*)&Hs[hbase+n];
        h[n]=h4.x; h[n+1]=h4.y; h[n+2]=h4.z; h[n+3]=h4.w;
    }
    const float* dl = delta + ((size_t)(b*SEQ + t0))*D_INNER + d;
    const float* ul = u     + ((size_t)(b*SEQ + t0))*D_INNER + d;
    const float* zl = xz    + ((size_t)(b*SEQ + t0))*2048 + 1024 + d;
    float*       yl = yout  + ((size_t)(b*SEQ + t0))*2048 + d;
    for (int t = 0; t < CL; ++t) {
        float dv = dl[(size_t)t*D_INNER];
        float uv = ul[(size_t)t*D_INNER];
        float zv = zl[(size_t)t*2048];
        float du = dv * uv;
        float y = 0.f;
#pragma unroll
        for (int n = 0; n < D_STATE; ++n) {
            float dA = exp2f(dv * A2[n]);
            h[n] = fmaf(dA, h[n], Bsh[t][n] * du);
            y = fmaf(h[n], Csh[t][n], y);
        }
        y = fmaf(uv, Dd, y);
        float sig = 1.f / (1.f + __expf(-zv));
        yl[(size_t)t*2048] = y * (zv * sig);
    }
}

extern "C" void kernel_launch(void* const* d_in, const int* in_sizes, int n_in,
                              void* d_out, int out_size, void* d_ws, size_t ws_size,
                              hipStream_t stream) {
    const float* x_in   = (const float*)d_in[0];
    const float* norm_w = (const float*)d_in[1];
    const float* norm_b = (const float*)d_in[2];
    const float* in_w   = (const float*)d_in[3];
    const float* conv_w = (const float*)d_in[4];
    const float* conv_b = (const float*)d_in[5];
    const float* xp_w   = (const float*)d_in[6];
    const float* dt_w   = (const float*)d_in[7];
    const float* dt_b   = (const float*)d_in[8];
    const float* A_log  = (const float*)d_in[9];
    const float* Dp     = (const float*)d_in[10];
    const float* out_w  = (const float*)d_in[11];
    float* out = (float*)d_out;

    // workspace layout (floats). total = 42.5M floats = 170 MB
    float* ws   = (float*)d_ws;
    float* xn   = ws;                                // 4M
    float* xz   = xn   + (size_t)NTOK*D_MODEL;       // 16M (xi | z); y aliased into xi half
    float* ub   = xz   + (size_t)NTOK*2048;          // 8M
    float* xdbl = ub   + (size_t)NTOK*D_INNER;       // 0.5M (dt | B | C)
    float* dlt  = xdbl + (size_t)NTOK*64;            // 8M
    float* Pb   = dlt  + (size_t)NTOK*D_INNER;       // 2M
    float* Sb   = Pb   + (size_t)BATCH*D_INNER*NCHUNK*16;  // 2M
    float* Hsb  = Sb   + (size_t)BATCH*D_INNER*NCHUNK*16;  // 2M

    for (int l = 0; l < N_LAYERS; ++l) {
        const float* xcur = (l == 0) ? x_in : out;
        ln_kernel<<<NTOK/4, 256, 0, stream>>>(xcur, norm_w + l*D_MODEL, norm_b + l*D_MODEL, xn);
        // xz = xn @ in_w^T   (M=8192, N=2048, K=512)
        gemm_nt128<<<dim3(2048/128, NTOK/128), 256, 0, stream>>>(
            xn, D_MODEL, in_w + (size_t)l*2*D_INNER*D_MODEL, D_MODEL, xz, 2048, nullptr, D_MODEL);
        conv_silu<<<(NTOK*D_INNER)/256, 256, 0, stream>>>(
            xz, conv_w + (size_t)l*D_INNER*D_CONV, conv_b + (size_t)l*D_INNER, ub);
        // xdbl = u @ xp_w^T  (M=8192, N=64, K=1024)
        gemm_nt<<<dim3(1, NTOK/64), 256, 0, stream>>>(
            ub, D_INNER, xp_w + (size_t)l*(DT_RANK+2*D_STATE)*D_INNER, D_INNER, xdbl, 64, nullptr, D_INNER);
        dt_softplus<<<NTOK, 256, 0, stream>>>(
            xdbl, dt_w + (size_t)l*D_INNER*DT_RANK, dt_b + (size_t)l*D_INNER, dlt);
        // chunked scan
        scan_partial<<<dim3(D_INNER/256, NCHUNK, BATCH), 256, 0, stream>>>(
            dlt, ub, xdbl, A_log + (size_t)l*D_INNER*D_STATE, Pb, Sb);
        scan_boundary<<<16, 256, 0, stream>>>(Pb, Sb, Hsb);
        scan_final<<<dim3(D_INNER/256, NCHUNK, BATCH), 256, 0, stream>>>(
            dlt, ub, xz, xz, xdbl, A_log + (size_t)l*D_INNER*D_STATE, Dp + (size_t)l*D_INNER, Hsb);
        // out = y @ out_w^T + xcur  (M=8192, N=512, K=1024); y has ld 2048 (aliased)
        gemm_nt128<<<dim3(D_MODEL/128, NTOK/128), 256, 0, stream>>>(
            xz, 2048, out_w + (size_t)l*D_MODEL*D_INNER, D_INNER, out, D_MODEL, xcur, D_INNER);
    }
}

// Round 3
// 1706.034 us; speedup vs baseline: 1.8173x; 1.8173x over previous
//
#include <hip/hip_runtime.h>
#include <math.h>

#define D_MODEL 512
#define N_LAYERS 4
#define D_STATE 16
#define D_CONV 4
#define D_INNER 1024
#define DT_RANK 32
#define BATCH 4
#define SEQ 2048
#define NTOK (BATCH*SEQ)   // 8192
#define NCHUNK 32
#define CL (SEQ/NCHUNK)    // 64
#define LOG2E 1.44269504f

typedef unsigned short ushort_t;
typedef __attribute__((ext_vector_type(8))) short bf8_t;
typedef __attribute__((ext_vector_type(4))) float f4_t;

__device__ __forceinline__ ushort_t f2bf(float f) {
    unsigned u = __float_as_uint(f);
    u += 0x7fffu + ((u >> 16) & 1u);
    return (ushort_t)(u >> 16);
}
__device__ __forceinline__ float bf2f(ushort_t h) {
    return __uint_as_float(((unsigned)h) << 16);
}
// async global->LDS, 16B per lane. lds dest must be wave-uniform base (+lane*16 by HW).
__device__ __forceinline__ void gload_lds16(const void* g, void* l) {
    auto* gp = (const __attribute__((address_space(1))) unsigned int*)(unsigned long long)(g);
    auto* lp = (__attribute__((address_space(3))) unsigned int*)(unsigned int)(unsigned long long)(l);
    __builtin_amdgcn_global_load_lds(gp, lp, 16, 0, 0);
}

// ---------------- LayerNorm -> bf16 hi/lo split output ----------------
__global__ __launch_bounds__(256) void ln_kernel(const float* __restrict__ x,
                          const float* __restrict__ w, const float* __restrict__ b,
                          ushort_t* __restrict__ hi, ushort_t* __restrict__ lo)
{
    int wave = threadIdx.x >> 6;
    int lane = threadIdx.x & 63;
    int row = blockIdx.x * 4 + wave;
    const float* xr = x + (size_t)row * D_MODEL;
    float v[8];
    float s = 0.f;
#pragma unroll
    for (int i = 0; i < 8; ++i) { v[i] = xr[lane + i*64]; s += v[i]; }
#pragma unroll
    for (int off = 32; off > 0; off >>= 1) s += __shfl_xor(s, off, 64);
    float mu = s * (1.f/512.f);
    float q = 0.f;
#pragma unroll
    for (int i = 0; i < 8; ++i) { float d = v[i]-mu; q += d*d; }
#pragma unroll
    for (int off = 32; off > 0; off >>= 1) q += __shfl_xor(q, off, 64);
    float rstd = rsqrtf(q * (1.f/512.f) + 1e-5f);
#pragma unroll
    for (int i = 0; i < 8; ++i) {
        int e = lane + i*64;
        float vv = (v[i]-mu)*rstd*w[e] + b[e];
        ushort_t h = f2bf(vv);
        hi[(size_t)row*D_MODEL + e] = h;
        lo[(size_t)row*D_MODEL + e] = f2bf(vv - bf2f(h));
    }
}

// ---------------- split fp32 weights -> bf16 hi/lo ----------------
__global__ __launch_bounds__(256) void split_w(const float* __restrict__ src,
        ushort_t* __restrict__ hi, ushort_t* __restrict__ lo, int n4)
{
    int i = blockIdx.x*256 + threadIdx.x;
    if (i >= n4) return;
    float4 v = ((const float4*)src)[i];
    ushort_t h0=f2bf(v.x), h1=f2bf(v.y), h2=f2bf(v.z), h3=f2bf(v.w);
    ushort4 hv = make_ushort4(h0,h1,h2,h3);
    ushort4 lv = make_ushort4(f2bf(v.x-bf2f(h0)), f2bf(v.y-bf2f(h1)),
                              f2bf(v.z-bf2f(h2)), f2bf(v.w-bf2f(h3)));
    ((ushort4*)hi)[i] = hv;
    ((ushort4*)lo)[i] = lv;
}

// ------- bf16 split-MFMA NT GEMM: C = (Ah+Al)@(Bh+Bl)^T (+resid) -------
// BMxBN tile, BK=32, 256 threads = 4 waves (2x2), 16x16x32 MFMA, 3-term split.
template<int BM, int BN, bool RES>
__global__ __launch_bounds__(256) void gemm_bf16s(
    const ushort_t* __restrict__ Ahi, const ushort_t* __restrict__ Alo, int lda,
    const ushort_t* __restrict__ Bhi, const ushort_t* __restrict__ Blo, int ldb,
    float* __restrict__ C, int ldc, const float* __restrict__ resid, int K)
{
    constexpr int MR = BM/32, NR = BN/32;
    __shared__ __align__(16) char lds[(2*BM + 2*BN)*64];
    char* lAh = lds;
    char* lAl = lds + BM*64;
    char* lBh = lds + 2*BM*64;
    char* lBl = lds + 2*BM*64 + BN*64;
    int tid = threadIdx.x;
    int lane = tid & 63, wave = tid >> 6;
    int row0 = blockIdx.y * BM, col0 = blockIdx.x * BN;
    int wr = wave >> 1, wc = wave & 1;
    f4_t acc[MR][NR];
#pragma unroll
    for (int m=0;m<MR;++m)
#pragma unroll
        for (int n=0;n<NR;++n)
#pragma unroll
            for (int j=0;j<4;++j) acc[m][n][j] = 0.f;

    int srow = tid >> 2;            // 0..63 (tile row per staging issue)
    int scol = (tid & 3) * 8;       // ushort offset within row
    int koff = (lane >> 4) * 16;    // byte offset of k-octet in 64B LDS row
    int fr = lane & 15;

    for (int k0 = 0; k0 < K; k0 += 32) {
        __syncthreads();
        gload_lds16(Ahi + (size_t)(row0 + srow)*lda + k0 + scol, lAh + wave*1024);
        gload_lds16(Alo + (size_t)(row0 + srow)*lda + k0 + scol, lAl + wave*1024);
        if (BM == 128) {
            gload_lds16(Ahi + (size_t)(row0 + 64 + srow)*lda + k0 + scol, lAh + 4096 + wave*1024);
            gload_lds16(Alo + (size_t)(row0 + 64 + srow)*lda + k0 + scol, lAl + 4096 + wave*1024);
        }
        gload_lds16(Bhi + (size_t)(col0 + srow)*ldb + k0 + scol, lBh + wave*1024);
        gload_lds16(Blo + (size_t)(col0 + srow)*ldb + k0 + scol, lBl + wave*1024);
        if (BN == 128) {
            gload_lds16(Bhi + (size_t)(col0 + 64 + srow)*ldb + k0 + scol, lBh + 4096 + wave*1024);
            gload_lds16(Blo + (size_t)(col0 + 64 + srow)*ldb + k0 + scol, lBl + 4096 + wave*1024);
        }
        __syncthreads();
        bf8_t ah[MR], al[MR], bh[NR], bl[NR];
#pragma unroll
        for (int m=0;m<MR;++m) {
            int r = wr*(BM/2) + m*16 + fr;
            ah[m] = *(const bf8_t*)(lAh + r*64 + koff);
            al[m] = *(const bf8_t*)(lAl + r*64 + koff);
        }
#pragma unroll
        for (int n=0;n<NR;++n) {
            int c = wc*(BN/2) + n*16 + fr;
            bh[n] = *(const bf8_t*)(lBh + c*64 + koff);
            bl[n] = *(const bf8_t*)(lBl + c*64 + koff);
        }
#pragma unroll
        for (int m=0;m<MR;++m)
#pragma unroll
            for (int n=0;n<NR;++n) {
                acc[m][n] = __builtin_amdgcn_mfma_f32_16x16x32_bf16(ah[m], bh[n], acc[m][n], 0,0,0);
                acc[m][n] = __builtin_amdgcn_mfma_f32_16x16x32_bf16(ah[m], bl[n], acc[m][n], 0,0,0);
                acc[m][n] = __builtin_amdgcn_mfma_f32_16x16x32_bf16(al[m], bh[n], acc[m][n], 0,0,0);
            }
    }
    int fq = (lane >> 4) * 4;
#pragma unroll
    for (int m=0;m<MR;++m)
#pragma unroll
        for (int n=0;n<NR;++n)
#pragma unroll
            for (int j=0;j<4;++j) {
                int r = row0 + wr*(BM/2) + m*16 + fq + j;
                int c = col0 + wc*(BN/2) + n*16 + fr;
                float v = acc[m][n][j];
                if (RES) v += resid[(size_t)r*ldc + c];
                C[(size_t)r*ldc + c] = v;
            }
}

// ---------------- causal depthwise conv (k=4) + SiLU ----------------
__global__ __launch_bounds__(256) void conv_silu(const float* __restrict__ xz,
                        const float* __restrict__ cw, const float* __restrict__ cb,
                        float* __restrict__ u)
{
    int idx = blockIdx.x * 256 + threadIdx.x;   // (b*SEQ+t)*1024 + d
    int d = idx & (D_INNER-1);
    int t = (idx >> 10) & (SEQ-1);
    float w0 = cw[d*4+0], w1 = cw[d*4+1], w2 = cw[d*4+2], w3 = cw[d*4+3];
    float s = cb[d];
    const float* base = xz + ((size_t)(idx >> 10))*2048 + d;
    if (t >= 3) s = fmaf(w0, base[-3*2048], s);
    if (t >= 2) s = fmaf(w1, base[-2*2048], s);
    if (t >= 1) s = fmaf(w2, base[-1*2048], s);
    s = fmaf(w3, base[0], s);
    u[idx] = s / (1.f + __expf(-s));
}

// ------- x_proj fp32 GEMM, 64x64 tile, K-split x2 via atomicAdd -------
__global__ __launch_bounds__(256) void gemm_xproj(const float* __restrict__ A,
                        const float* __restrict__ B, float* __restrict__ C)
{
    __shared__ float As[16][68];
    __shared__ float Bs[16][68];
    int tid = threadIdx.x;
    int tx = tid & 15, ty = tid >> 4;
    int row0 = blockIdx.y * 64;
    int kbeg = blockIdx.x * 512;
    int lr = tid >> 2;
    int lk = (tid & 3) << 2;
    float acc[4][4] = {};
    const float* Ap = A + (size_t)(row0+lr)*D_INNER + kbeg + lk;
    const float* Bp = B + (size_t)lr*D_INNER + kbeg + lk;
    for (int k0 = 0; k0 < 512; k0 += 16) {
        float4 a4 = *(const float4*)(Ap + k0);
        float4 b4 = *(const float4*)(Bp + k0);
        __syncthreads();
        As[lk+0][lr]=a4.x; As[lk+1][lr]=a4.y; As[lk+2][lr]=a4.z; As[lk+3][lr]=a4.w;
        Bs[lk+0][lr]=b4.x; Bs[lk+1][lr]=b4.y; Bs[lk+2][lr]=b4.z; Bs[lk+3][lr]=b4.w;
        __syncthreads();
#pragma unroll
        for (int k = 0; k < 16; ++k) {
            float ar[4], br[4];
#pragma unroll
            for (int i=0;i<4;++i) ar[i] = As[k][ty*4+i];
#pragma unroll
            for (int j=0;j<4;++j) br[j] = Bs[k][tx*4+j];
#pragma unroll
            for (int i=0;i<4;++i)
#pragma unroll
                for (int j=0;j<4;++j) acc[i][j] = fmaf(ar[i], br[j], acc[i][j]);
        }
    }
#pragma unroll
    for (int i=0;i<4;++i)
#pragma unroll
        for (int j=0;j<4;++j)
            atomicAdd(&C[(size_t)(row0+ty*4+i)*64 + tx*4+j], acc[i][j]);
}

// ---------------- dt_proj (K=32) + bias + softplus, 8 tokens/block ----------------
__global__ __launch_bounds__(256) void dt_softplus(const float* __restrict__ xdbl,
                        const float* __restrict__ dtw, const float* __restrict__ dtb,
                        float* __restrict__ delta)
{
    __shared__ float xr[8][32];
    int t0 = blockIdx.x * 8;
    int tid = threadIdx.x;
    {
        int tt = tid >> 5, r = tid & 31;
        xr[tt][r] = xdbl[(size_t)(t0+tt)*64 + r];
    }
    __syncthreads();
#pragma unroll
    for (int jj = 0; jj < 4; ++jj) {
        int j = (jj<<8) + tid;
        const float* w = dtw + (size_t)j*DT_RANK;
        float bj = dtb[j];
        float acc[8];
#pragma unroll
        for (int tt=0;tt<8;++tt) acc[tt]=bj;
#pragma unroll
        for (int r=0;r<DT_RANK;r+=4){
            float4 w4 = *(const float4*)(w+r);
#pragma unroll
            for (int tt=0;tt<8;++tt){
                acc[tt] = fmaf(xr[tt][r+0], w4.x, acc[tt]);
                acc[tt] = fmaf(xr[tt][r+1], w4.y, acc[tt]);
                acc[tt] = fmaf(xr[tt][r+2], w4.z, acc[tt]);
                acc[tt] = fmaf(xr[tt][r+3], w4.w, acc[tt]);
            }
        }
#pragma unroll
        for (int tt=0;tt<8;++tt){
            float s = acc[tt];
            float sp = fmaxf(s,0.f) + log1pf(__expf(-fabsf(s)));
            delta[(size_t)(t0+tt)*D_INNER + j] = sp;
        }
    }
}

// ======== chunked parallel selective scan: 3 passes ========
__global__ __launch_bounds__(256) void scan_partial(const float* __restrict__ delta,
                        const float* __restrict__ u,
                        const float* __restrict__ xdbl,
                        const float* __restrict__ A_log,
                        float* __restrict__ P, float* __restrict__ S)
{
    int d = blockIdx.x * 256 + threadIdx.x;
    int c = blockIdx.y;
    int b = blockIdx.z;
    int t0 = c * CL;
    __shared__ float Bsh[CL][16];
    for (int i = threadIdx.x; i < CL*16; i += 256) {
        int tt = i >> 4, n = i & 15;
        Bsh[tt][n] = xdbl[((size_t)(b*SEQ + t0 + tt))*64 + 32 + n];
    }
    __syncthreads();
    float A2[D_STATE];
#pragma unroll
    for (int n = 0; n < D_STATE; ++n)
        A2[n] = -expf(A_log[(size_t)d*D_STATE + n]) * LOG2E;
    float p[D_STATE], h[D_STATE];
#pragma unroll
    for (int n = 0; n < D_STATE; ++n) { p[n] = 1.f; h[n] = 0.f; }
    const float* dl = delta + ((size_t)(b*SEQ + t0))*D_INNER + d;
    const float* ul = u     + ((size_t)(b*SEQ + t0))*D_INNER + d;
    for (int t = 0; t < CL; ++t) {
        float dv = dl[(size_t)t*D_INNER];
        float uv = ul[(size_t)t*D_INNER];
        float du = dv * uv;
#pragma unroll
        for (int n = 0; n < D_STATE; ++n) {
            float dA = exp2f(dv * A2[n]);
            p[n] *= dA;
            h[n] = fmaf(dA, h[n], Bsh[t][n] * du);
        }
    }
    size_t base = (((size_t)b*D_INNER + d)*NCHUNK + c)*16;
#pragma unroll
    for (int n = 0; n < D_STATE; n += 4) {
        *(float4*)&P[base+n] = make_float4(p[n],p[n+1],p[n+2],p[n+3]);
        *(float4*)&S[base+n] = make_float4(h[n],h[n+1],h[n+2],h[n+3]);
    }
}

__global__ __launch_bounds__(256) void scan_boundary(const float* __restrict__ P,
                        const float* __restrict__ S, float* __restrict__ Hs)
{
    int b = blockIdx.x >> 2;
    int d = ((blockIdx.x & 3) << 8) + threadIdx.x;
    size_t base = ((size_t)b*D_INNER + d)*NCHUNK*16;
    float h[D_STATE];
#pragma unroll
    for (int n = 0; n < D_STATE; ++n) h[n] = 0.f;
    for (int c = 0; c < NCHUNK; ++c) {
        size_t o = base + (size_t)c*16;
#pragma unroll
        for (int n = 0; n < D_STATE; n += 4) {
            *(float4*)&Hs[o+n] = make_float4(h[n],h[n+1],h[n+2],h[n+3]);
            float4 p4 = *(const float4*)&P[o+n];
            float4 s4 = *(const float4*)&S[o+n];
            h[n+0] = fmaf(p4.x, h[n+0], s4.x);
            h[n+1] = fmaf(p4.y, h[n+1], s4.y);
            h[n+2] = fmaf(p4.z, h[n+2], s4.z);
            h[n+3] = fmaf(p4.w, h[n+3], s4.w);
        }
    }
}

// Pass C: re-scan chunk, y=(scan+u*D)*silu(z) -> bf16 hi/lo into xi half of xz
__global__ __launch_bounds__(256) void scan_final(const float* __restrict__ delta,
                        const float* __restrict__ u,
                        float* __restrict__ xz,
                        const float* __restrict__ xdbl,
                        const float* __restrict__ A_log,
                        const float* __restrict__ Dp,
                        const float* __restrict__ Hs)
{
    int d = blockIdx.x * 256 + threadIdx.x;
    int c = blockIdx.y;
    int b = blockIdx.z;
    int t0 = c * CL;
    __shared__ float Bsh[CL][16];
    __shared__ float Csh[CL][16];
    for (int i = threadIdx.x; i < CL*16; i += 256) {
        int tt = i >> 4, n = i & 15;
        size_t xo = ((size_t)(b*SEQ + t0 + tt))*64;
        Bsh[tt][n] = xdbl[xo + 32 + n];
        Csh[tt][n] = xdbl[xo + 48 + n];
    }
    __syncthreads();
    float A2[D_STATE];
#pragma unroll
    for (int n = 0; n < D_STATE; ++n)
        A2[n] = -expf(A_log[(size_t)d*D_STATE + n]) * LOG2E;
    float Dd = Dp[d];
    float h[D_STATE];
    size_t hbase = (((size_t)b*D_INNER + d)*NCHUNK + c)*16;
#pragma unroll
    for (int n = 0; n < D_STATE; n += 4) {
        float4 h4 = *(const float4*)&Hs[hbase+n];
        h[n]=h4.x; h[n+1]=h4.y; h[n+2]=h4.z; h[n+3]=h4.w;
    }
    const float* dl = delta + ((size_t)(b*SEQ + t0))*D_INNER + d;
    const float* ul = u     + ((size_t)(b*SEQ + t0))*D_INNER + d;
    const float* zl = xz    + ((size_t)(b*SEQ + t0))*2048 + 1024 + d;
    ushort_t* yrow = (ushort_t*)(xz + ((size_t)(b*SEQ + t0))*2048);
    for (int t = 0; t < CL; ++t) {
        float dv = dl[(size_t)t*D_INNER];
        float uv = ul[(size_t)t*D_INNER];
        float zv = zl[(size_t)t*2048];
        float du = dv * uv;
        float y = 0.f;
#pragma unroll
        for (int n = 0; n < D_STATE; ++n) {
            float dA = exp2f(dv * A2[n]);
            h[n] = fmaf(dA, h[n], Bsh[t][n] * du);
            y = fmaf(h[n], Csh[t][n], y);
        }
        y = fmaf(uv, Dd, y);
        float sig = 1.f / (1.f + __expf(-zv));
        float yg = y * (zv * sig);
        ushort_t yh = f2bf(yg);
        yrow[(size_t)t*4096 + d] = yh;
        yrow[(size_t)t*4096 + 1024 + d] = f2bf(yg - bf2f(yh));
    }
}

extern "C" void kernel_launch(void* const* d_in, const int* in_sizes, int n_in,
                              void* d_out, int out_size, void* d_ws, size_t ws_size,
                              hipStream_t stream) {
    const float* x_in   = (const float*)d_in[0];
    const float* norm_w = (const float*)d_in[1];
    const float* norm_b = (const float*)d_in[2];
    const float* in_w   = (const float*)d_in[3];
    const float* conv_w = (const float*)d_in[4];
    const float* conv_b = (const float*)d_in[5];
    const float* xp_w   = (const float*)d_in[6];
    const float* dt_w   = (const float*)d_in[7];
    const float* dt_b   = (const float*)d_in[8];
    const float* A_log  = (const float*)d_in[9];
    const float* Dp     = (const float*)d_in[10];
    const float* out_w  = (const float*)d_in[11];
    float* out = (float*)d_out;

    // workspace layout (~168 MB, <= round-2 footprint which ran fine)
    float* ws   = (float*)d_ws;
    float* xz   = ws;                          // 8192*2048 f32 (xi|z); y hi/lo bf16 later aliased into xi bytes
    float* ub   = xz   + (size_t)NTOK*2048;    // 8192*1024 f32
    float* xdbl = ub   + (size_t)NTOK*D_INNER; // 8192*64 f32
    float* dlt  = xdbl + (size_t)NTOK*64;      // 8192*1024 f32 (head 16MB doubles as xnh/xnl)
    float* Pb   = dlt  + (size_t)NTOK*D_INNER;
    float* Sb   = Pb   + (size_t)BATCH*D_INNER*NCHUNK*16;
    float* Hsb  = Sb   + (size_t)BATCH*D_INNER*NCHUNK*16;
    ushort_t* wih = (ushort_t*)(Hsb + (size_t)BATCH*D_INNER*NCHUNK*16);
    ushort_t* wil = wih + (size_t)2*D_INNER*D_MODEL;
    ushort_t* woh = wil + (size_t)2*D_INNER*D_MODEL;
    ushort_t* wol = woh + (size_t)D_MODEL*D_INNER;
    // xn hi/lo alias dlt head (dead by the time dt_softplus writes dlt)
    ushort_t* xnh = (ushort_t*)dlt;
    ushort_t* xnl = xnh + (size_t)NTOK*D_MODEL;

    for (int l = 0; l < N_LAYERS; ++l) {
        const float* xcur = (l == 0) ? x_in : out;
        split_w<<<1024, 256, 0, stream>>>(in_w + (size_t)l*2*D_INNER*D_MODEL, wih, wil, 2*D_INNER*D_MODEL/4);
        split_w<<<512, 256, 0, stream>>>(out_w + (size_t)l*D_MODEL*D_INNER, woh, wol, D_MODEL*D_INNER/4);
        ln_kernel<<<NTOK/4, 256, 0, stream>>>(xcur, norm_w + l*D_MODEL, norm_b + l*D_MODEL, xnh, xnl);
        // xz = xn @ in_w^T   (M=8192, N=2048, K=512)
        gemm_bf16s<128,128,false><<<dim3(2048/128, NTOK/128), 256, 0, stream>>>(
            xnh, xnl, D_MODEL, wih, wil, D_MODEL, xz, 2048, nullptr, D_MODEL);
        conv_silu<<<(NTOK*D_INNER)/256, 256, 0, stream>>>(
            xz, conv_w + (size_t)l*D_INNER*D_CONV, conv_b + (size_t)l*D_INNER, ub);
        // xdbl = u @ xp_w^T  (M=8192, N=64, K=1024), K-split x2 + atomicAdd
        hipMemsetAsync(xdbl, 0, (size_t)NTOK*64*sizeof(float), stream);
        gemm_xproj<<<dim3(2, NTOK/64), 256, 0, stream>>>(
            ub, xp_w + (size_t)l*(DT_RANK+2*D_STATE)*D_INNER, xdbl);
        dt_softplus<<<NTOK/8, 256, 0, stream>>>(
            xdbl, dt_w + (size_t)l*D_INNER*DT_RANK, dt_b + (size_t)l*D_INNER, dlt);
        scan_partial<<<dim3(D_INNER/256, NCHUNK, BATCH), 256, 0, stream>>>(
            dlt, ub, xdbl, A_log + (size_t)l*D_INNER*D_STATE, Pb, Sb);
        scan_boundary<<<16, 256, 0, stream>>>(Pb, Sb, Hsb);
        scan_final<<<dim3(D_INNER/256, NCHUNK, BATCH), 256, 0, stream>>>(
            dlt, ub, xz, xdbl, A_log + (size_t)l*D_INNER*D_STATE, Dp + (size_t)l*D_INNER, Hsb);
        // out = y @ out_w^T + xcur  (M=8192, N=512, K=1024); y bf16 hi/lo packed in xz rows
        gemm_bf16s<64,128,true><<<dim3(D_MODEL/128, NTOK/64), 256, 0, stream>>>(
            (const ushort_t*)xz, (const ushort_t*)xz + 1024, 4096,
            woh, wol, D_INNER, out, D_MODEL, xcur, D_INNER);
    }
}